// Round 20
// baseline (152.323 us; speedup 1.0000x reference)
//
#include <hip/hip_runtime.h>
#include <math.h>

#define DIMC 64
#define NE 512
#define HWSZ 4096              // 64*64
#define NPTS 131072
#define DECAYF 0.99f
#define OMD 0.01f
#define EPSF 1e-5f
#define MARGIN 1e-3f

// output offsets (floats) — out0 is [32,64,64,64] = 8388608 elements
#define O0 0
#define O1 8388608                 // diff scalar
#define O2 8388609                 // embed_ind [32,64,64]
#define O3 8519681                 // new_cluster_size [512]
#define O4 8520193                 // new_dictionary_avg [64,512]
#define O5 8552961                 // new_dictionary [64,512]
#define O6 8585729                 // mean_D scalar

// ws float-offset layout
#define WS_DIFF   0
#define WS_ESUM   64                       // [c][j] 64*512 f32 (reduced)
#define WS_COUNTS 32832                    // 512 f32 (contiguous after ESUM)
#define WS_DT     33344                    // [j][c] dictT f32, 32768
#define WS_NORM   66112                    // 512: -0.5*||d_j||^2
#define WS_DHI    66624                    // 512x64 bf16 (16384 floats)
#define WS_DLO    83008                    // 512x64 bf16
#define WS_BIDX   99392                    // NPTS ints (gap region)
#define WS_PART   246852                   // f32 partials: NBLK x 33280
#define PART_STRIDE 33280                  // 32768 esum + 512 counts
#define NBLK 256
#define WS_NEED_BYTES ((size_t)(WS_PART + (size_t)NBLK * PART_STRIDE) * 4)

typedef __attribute__((ext_vector_type(8))) short bf16x8;
typedef __attribute__((ext_vector_type(4))) float f32x4;

__device__ __forceinline__ unsigned bf16rne(float x) {
    unsigned u = __float_as_uint(x);
    return (u + 0x7FFFu + ((u >> 16) & 1u)) >> 16;
}

// -------- K1: dictT f32 + bf16 hi/lo + norms + zero accumulators --------
__global__ void k_prep(const float* __restrict__ dict, float* __restrict__ ws) {
    int j = blockIdx.x, c = threadIdx.x;
    float v = dict[c * NE + j];
    ws[WS_DT + j * DIMC + c] = v;
    unsigned h = bf16rne(v);
    float fh = __uint_as_float(h << 16);
    unsigned l = bf16rne(v - fh);
    ((unsigned short*)(ws + WS_DHI))[j * DIMC + c] = (unsigned short)h;
    ((unsigned short*)(ws + WS_DLO))[j * DIMC + c] = (unsigned short)l;
    ws[WS_ESUM + j * DIMC + c] = 0.f;      // reduce target (atomic-accumulated)
    if (c == 0) ws[WS_COUNTS + j] = 0.f;
    if (j == 0 && c == 0) ws[WS_DIFF] = 0.f;
    float s = v * v;
    #pragma unroll
    for (int off = 32; off > 0; off >>= 1) s += __shfl_down(s, off);
    if (c == 0) ws[WS_NORM + j] = -0.5f * s;
}

#define MFMA16(A, B, C) __builtin_amdgcn_mfma_f32_16x16x32_bf16(A, B, C, 0, 0, 0)

// -------- K2a: MFMA score, STATIC LDS (50 KB), 8-pass dict staging --------
// 512 blocks x 512 threads (8 waves); wave computes 32 points x 512 codes.
// Static __shared__ (vs dynamic) to allow multi-block co-residency.
__global__ __launch_bounds__(512, 1) void k_score(
        const float* __restrict__ x, float* __restrict__ ws) {
    __shared__ uint4 ldh[512];             // pass dict hi (8 KB), swizzled
    __shared__ uint4 ldl[512];             // pass dict lo (8 KB)
    __shared__ float lnrm[512];            // 2 KB
    __shared__ char  stgB[32768];          // x staging (hi then lo); overlaid
    __shared__ int   lcnt;
    int* bidxl  = (int*)stgB;              // overlay after frag loads: 256
    int* lflist = (int*)stgB + 256;

    const int tid  = threadIdx.x;
    const int lane = tid & 63;
    const int w    = tid >> 6;

    const int nb  = blockIdx.x * 256;
    const int b   = nb >> 12;
    const int hwb = nb & 4095;

    const uint4* gdh = (const uint4*)(ws + WS_DHI);   // 4096 uint4 total
    const uint4* gdl = (const uint4*)(ws + WS_DLO);

    // ---- stage dict pass 0 (codes 0..63, hi+lo) + norms ----
    {
        const int cl = tid >> 3, ch = tid & 7;         // code_local, chunk
        const int dp = cl * 8 + (ch ^ (cl & 7));
        ldh[dp] = gdh[tid];
        ldl[dp] = gdl[tid];
        lnrm[tid] = ws[WS_NORM + tid];
    }

    // ---- staged x load: thread = (half h, point p); 32 c's each ----
    const int p = tid & 255, h = tid >> 8;
    const float* xp = x + (size_t)b * (DIMC * HWSZ) + (size_t)(32 * h) * HWSZ
                        + hwb + p;
    unsigned hiu[16], lou[16];
    #pragma unroll
    for (int i = 0; i < 16; ++i) {
        float v0 = xp[(2 * i) * HWSZ];
        float v1 = xp[(2 * i + 1) * HWSZ];
        unsigned h0 = bf16rne(v0), h1 = bf16rne(v1);
        float r0 = v0 - __uint_as_float(h0 << 16);
        float r1 = v1 - __uint_as_float(h1 << 16);
        hiu[i] = h0 | (h1 << 16);
        lou[i] = bf16rne(r0) | (bf16rne(r1) << 16);
    }
    const int swz = p & 7;
    #pragma unroll
    for (int k = 0; k < 4; ++k) {
        uint4 u = {hiu[4 * k], hiu[4 * k + 1], hiu[4 * k + 2], hiu[4 * k + 3]};
        *(uint4*)(stgB + p * 128 + (((4 * h + k) ^ swz) << 4)) = u;
    }
    __syncthreads();

    // ---- A-fragments hi (row = w*32 + pt*16 + (lane&15)) ----
    bf16x8 ahi[2][2], alo[2][2];
    #pragma unroll
    for (int pt = 0; pt < 2; ++pt) {
        const int row = (w << 5) + (pt << 4) + (lane & 15);
        #pragma unroll
        for (int kk = 0; kk < 2; ++kk) {
            const int ch = (lane >> 4) + (kk << 2);
            ahi[pt][kk] = __builtin_bit_cast(bf16x8,
                *(const uint4*)(stgB + row * 128 + ((ch ^ (row & 7)) << 4)));
        }
    }
    __syncthreads();

    // ---- stage x lo (same buffer), read lo frags ----
    #pragma unroll
    for (int k = 0; k < 4; ++k) {
        uint4 u = {lou[4 * k], lou[4 * k + 1], lou[4 * k + 2], lou[4 * k + 3]};
        *(uint4*)(stgB + p * 128 + (((4 * h + k) ^ swz) << 4)) = u;
    }
    __syncthreads();
    #pragma unroll
    for (int pt = 0; pt < 2; ++pt) {
        const int row = (w << 5) + (pt << 4) + (lane & 15);
        #pragma unroll
        for (int kk = 0; kk < 2; ++kk) {
            const int ch = (lane >> 4) + (kk << 2);
            alo[pt][kk] = __builtin_bit_cast(bf16x8,
                *(const uint4*)(stgB + row * 128 + ((ch ^ (row & 7)) << 4)));
        }
    }
    if (tid == 0) lcnt = 0;
    __syncthreads();   // staging dead -> stgB reusable as bidxl/lflist

    // ---- MFMA sweep: 8 passes x 4 code-tiles; B from LDS ----
    const int col = lane & 15, g = lane >> 4;
    const int cswz = col & 7;
    const float* nl = lnrm + col;

    float best[2][4], sec[2][4];
    int   idx[2][4];
    #pragma unroll
    for (int pt = 0; pt < 2; ++pt)
        #pragma unroll
        for (int r = 0; r < 4; ++r) {
            best[pt][r] = -3.4e38f; sec[pt][r] = -3.4e38f; idx[pt][r] = 0;
        }

    for (int pass = 0; pass < 8; ++pass) {
        if (pass) {
            __syncthreads();   // all waves done with previous pass dict
            const int cl = tid >> 3, ch = tid & 7;
            const int dp = cl * 8 + (ch ^ (cl & 7));
            ldh[dp] = gdh[pass * 512 + tid];
            ldl[dp] = gdl[pass * 512 + tid];
            __syncthreads();
        }

        #pragma unroll
        for (int tt = 0; tt < 4; ++tt) {
            const int base = (tt << 7) + (col << 3);
            uint4 uh0 = ldh[base + (g ^ cswz)];
            uint4 uh1 = ldh[base + ((g + 4) ^ cswz)];
            uint4 ul0 = ldl[base + (g ^ cswz)];
            uint4 ul1 = ldl[base + ((g + 4) ^ cswz)];
            const int jt = (pass << 2) + tt;
            float nrm = nl[jt << 4];
            bf16x8 bh0 = __builtin_bit_cast(bf16x8, uh0);
            bf16x8 bh1 = __builtin_bit_cast(bf16x8, uh1);
            bf16x8 bl0 = __builtin_bit_cast(bf16x8, ul0);
            bf16x8 bl1 = __builtin_bit_cast(bf16x8, ul1);
            const int jc = (jt << 4) + col;
            #pragma unroll
            for (int pt = 0; pt < 2; ++pt) {
                f32x4 acc = {0.f, 0.f, 0.f, 0.f};
                acc = MFMA16(ahi[pt][0], bh0, acc);
                acc = MFMA16(ahi[pt][1], bh1, acc);
                acc = MFMA16(ahi[pt][0], bl0, acc);
                acc = MFMA16(ahi[pt][1], bl1, acc);
                acc = MFMA16(alo[pt][0], bh0, acc);
                acc = MFMA16(alo[pt][1], bh1, acc);
                acc = MFMA16(alo[pt][0], bl0, acc);
                acc = MFMA16(alo[pt][1], bl1, acc);
                #pragma unroll
                for (int r = 0; r < 4; ++r) {
                    float s = acc[r] + nrm;
                    bool gt = s > best[pt][r];
                    float ns = gt ? best[pt][r] : (s > sec[pt][r] ? s : sec[pt][r]);
                    best[pt][r] = gt ? s : best[pt][r];
                    idx[pt][r]  = gt ? jc : idx[pt][r];
                    sec[pt][r]  = ns;
                }
            }
        }
    }

    // ---- argmax reduce across 16-lane code groups ----
    #pragma unroll
    for (int off = 8; off > 0; off >>= 1) {
        #pragma unroll
        for (int pt = 0; pt < 2; ++pt)
            #pragma unroll
            for (int r = 0; r < 4; ++r) {
                float ob = __shfl_xor(best[pt][r], off, 16);
                float os = __shfl_xor(sec[pt][r], off, 16);
                int   oi = __shfl_xor(idx[pt][r], off, 16);
                bool take = (ob > best[pt][r]) ||
                            (ob == best[pt][r] && oi < idx[pt][r]);
                float nsec = fmaxf(fminf(ob, best[pt][r]),
                                   fmaxf(os, sec[pt][r]));
                best[pt][r] = take ? ob : best[pt][r];
                idx[pt][r]  = take ? oi : idx[pt][r];
                sec[pt][r]  = nsec;
            }
    }
    if ((lane & 15) == 0) {
        const int gq = lane >> 4;
        #pragma unroll
        for (int pt = 0; pt < 2; ++pt)
            #pragma unroll
            for (int r = 0; r < 4; ++r) {
                int pp = (w << 5) + (pt << 4) + (gq << 2) + r;
                int flag = (best[pt][r] - sec[pt][r] < MARGIN) ? 65536 : 0;
                bidxl[pp] = idx[pt][r] | flag;
            }
    }
    __syncthreads();

    // ---- build flagged list ----
    if (tid < 256) {
        int e = bidxl[tid];
        if (e & 65536) {
            int pos = atomicAdd(&lcnt, 1);
            lflist[pos] = tid;
        }
    }
    __syncthreads();

    // ---- in-block exact rescan, one wave per flagged point --------------
    const float* dptr = ws + WS_DT;
    {
        const int nf = lcnt;
        for (int fi = w; fi < nf; fi += 8) {
            const int pp = lflist[fi];
            const float xv = x[(size_t)b * (DIMC * HWSZ)
                               + (size_t)lane * HWSZ + hwb + pp];
            float bb = -3.4e38f; int bj = 0;
            #pragma unroll 2
            for (int s = 0; s < 8; ++s) {
                const int j = (lane << 3) + s;
                const float4* row = (const float4*)(dptr + (size_t)j * DIMC);
                float a0 = 0.f, a1 = 0.f, a2 = 0.f, a3 = 0.f;
                #pragma unroll
                for (int c4 = 0; c4 < 16; ++c4) {
                    float4 r4 = row[c4];
                    a0 = fmaf(r4.x, __shfl(xv, 4 * c4 + 0), a0);
                    a1 = fmaf(r4.y, __shfl(xv, 4 * c4 + 1), a1);
                    a2 = fmaf(r4.z, __shfl(xv, 4 * c4 + 2), a2);
                    a3 = fmaf(r4.w, __shfl(xv, 4 * c4 + 3), a3);
                }
                float sc = ((a0 + a1) + (a2 + a3)) + lnrm[j];
                if (sc > bb) { bb = sc; bj = j; }
            }
            #pragma unroll
            for (int off = 1; off < 64; off <<= 1) {
                float ob = __shfl_xor(bb, off);
                int   oi = __shfl_xor(bj, off);
                bool take = (ob > bb) || (ob == bb && oi < bj);
                bb = take ? ob : bb;
                bj = take ? oi : bj;
            }
            if (lane == 0) bidxl[pp] = bj;
        }
    }
    __syncthreads();

    if (tid < 256) ((int*)ws)[WS_BIDX + nb + tid] = bidxl[tid] & 511;
}

// -------- K2b: gather/quantize/stats; all global stores post-barrier -----
__global__ __launch_bounds__(512, 1) void k_emit(
        const float* __restrict__ x, float* __restrict__ ws,
        float* __restrict__ out, int use_part) {
    extern __shared__ float lds[];
    float* esum  = lds;                 // 32768: esum_t [c][j]
    int*   lhist = (int*)(lds + 32768); // 512
    float* lred  = lds + 33280;         // 8

    const int tid = threadIdx.x;
    {
        float4 z = {0.f, 0.f, 0.f, 0.f};
        float4* e4 = (float4*)esum;
        #pragma unroll
        for (int k = 0; k < 16; ++k) e4[tid + 512 * k] = z;
        lhist[tid] = 0;
    }
    __syncthreads();

    const int n0 = blockIdx.x * 512 + tid;
    const int b = n0 >> 12, hw0 = n0 & 4095;
    const float* xp = x + (size_t)b * (DIMC * HWSZ) + hw0;
    float f0[DIMC];
    #pragma unroll
    for (int c = 0; c < DIMC; ++c) f0[c] = xp[c * HWSZ];

    const int bi0 = ((const int*)ws)[WS_BIDX + n0];
    atomicAdd(&lhist[bi0], 1);

    // esum scatter (LDS, banks spread by bidx)
    #pragma unroll
    for (int c = 0; c < DIMC; ++c) atomicAdd(&esum[c * NE + bi0], f0[c]);

    // q gather + diff partials (no stores yet)
    const float* dptr = ws + WS_DT;
    float ssum = 0.f;
    const float4* q40 = (const float4*)(dptr + (size_t)bi0 * DIMC);
    #pragma unroll
    for (int c4 = 0; c4 < 16; ++c4) {
        float4 qa = q40[c4];
        const int cb = 4 * c4;
        float d;
        d = qa.x - f0[cb + 0]; ssum = fmaf(d, d, ssum);
        d = qa.y - f0[cb + 1]; ssum = fmaf(d, d, ssum);
        d = qa.z - f0[cb + 2]; ssum = fmaf(d, d, ssum);
        d = qa.w - f0[cb + 3]; ssum = fmaf(d, d, ssum);
    }
    #pragma unroll
    for (int off = 32; off > 0; off >>= 1) ssum += __shfl_down(ssum, off);
    if ((tid & 63) == 0) lred[tid >> 6] = ssum;
    __syncthreads();

    // ---- post-barrier: all global stores (no trailing barrier/drain) ----
    if (use_part) {
        float* part = ws + WS_PART + (size_t)blockIdx.x * PART_STRIDE;
        float4* p4 = (float4*)part;
        const float4* e4 = (const float4*)esum;
        #pragma unroll
        for (int k = 0; k < 16; ++k) p4[tid + 512 * k] = e4[tid + 512 * k];
        part[32768 + tid] = (float)lhist[tid];
    } else {
        #pragma unroll
        for (int k = 0; k < 64; ++k)
            atomicAdd(&ws[WS_ESUM + tid + 512 * k], esum[tid + 512 * k]);
        atomicAdd(&ws[WS_COUNTS + tid], (float)lhist[tid]);
    }

    out[O2 + n0] = (float)bi0;
    float* o0 = out + O0 + (size_t)b * (DIMC * HWSZ) + hw0;
    #pragma unroll
    for (int c4 = 0; c4 < 16; ++c4) {
        float4 qa = q40[c4];        // re-gather (L2-hot)
        const int cb = 4 * c4;
        o0[(cb + 0) * HWSZ] = qa.x;
        o0[(cb + 1) * HWSZ] = qa.y;
        o0[(cb + 2) * HWSZ] = qa.z;
        o0[(cb + 3) * HWSZ] = qa.w;
    }

    if (tid == 0) {
        float t = 0.f;
        #pragma unroll
        for (int w2 = 0; w2 < 8; ++w2) t += lred[w2];
        atomicAdd(ws + WS_DIFF, t);
    }
}

// -------- K2d: parallel partial reduce (260 blocks, spread atomics) ------
__global__ void k_reduce(float* __restrict__ ws) {
    const int tid = threadIdx.x;
    const int gid = (blockIdx.x % 65) * 128 + tid;     // [0, 8320) float4 pos
    const int slice = blockIdx.x / 65;                  // [0, 4)
    const float4* src = (const float4*)(ws + WS_PART);
    float4 acc = {0.f, 0.f, 0.f, 0.f};
    const int p0 = slice * 64;
    #pragma unroll 4
    for (int p = p0; p < p0 + 64; ++p) {
        float4 v = src[(size_t)p * (PART_STRIDE / 4) + gid];
        acc.x += v.x; acc.y += v.y; acc.z += v.z; acc.w += v.w;
    }
    float* dst = ws + WS_ESUM + gid * 4;                // COUNTS follows ESUM
    atomicAdd(dst + 0, acc.x);
    atomicAdd(dst + 1, acc.y);
    atomicAdd(dst + 2, acc.z);
    atomicAdd(dst + 3, acc.w);
}

// -------- K3: finalize EMA buffers / outputs --------
__global__ void k_final(const float* __restrict__ ws,
                        const float* __restrict__ cluster_size,
                        const float* __restrict__ davg,
                        float* __restrict__ out) {
    __shared__ float red[16];
    __shared__ float nsh;
    const int j = threadIdx.x;

    float cnt = ws[WS_COUNTS + j];
    float ncs = DECAYF * cluster_size[j] + OMD * cnt;
    out[O3 + j] = ncs;

    float v = ncs;
    #pragma unroll
    for (int off = 32; off > 0; off >>= 1) v += __shfl_down(v, off);
    if ((j & 63) == 0) red[j >> 6] = v;
    __syncthreads();
    if (j == 0) {
        float t = 0.f;
        #pragma unroll
        for (int w = 0; w < 8; ++w) t += red[w];
        nsh = t;
    }
    __syncthreads();
    const float n = nsh;
    const float csj = (ncs + EPSF) / (n + NE * EPSF) * n;

    float asum = 0.f;
    #pragma unroll
    for (int c = 0; c < DIMC; ++c) {
        float es = ws[WS_ESUM + c * NE + j];
        float da = davg[c * NE + j];
        float nda = DECAYF * da + OMD * es;
        out[O4 + c * NE + j] = nda;
        float nd = nda / csj;
        out[O5 + c * NE + j] = nd;
        asum += fabsf(nd);
    }

    __syncthreads();
    #pragma unroll
    for (int off = 32; off > 0; off >>= 1) asum += __shfl_down(asum, off);
    if ((j & 63) == 0) red[j >> 6] = asum;
    __syncthreads();
    if (j == 0) {
        float t = 0.f;
        #pragma unroll
        for (int w = 0; w < 8; ++w) t += red[w];
        out[O6] = t / 32768.0f;
        out[O1] = ws[WS_DIFF] / 8388608.0f;
    }
}

extern "C" void kernel_launch(void* const* d_in, const int* in_sizes, int n_in,
                              void* d_out, int out_size, void* d_ws, size_t ws_size,
                              hipStream_t stream) {
    const float* x    = (const float*)d_in[0];
    const float* dict = (const float*)d_in[1];
    const float* csz  = (const float*)d_in[2];
    const float* davg = (const float*)d_in[3];
    float* out = (float*)d_out;
    float* ws  = (float*)d_ws;

    const int use_part = (ws_size >= WS_NEED_BYTES) ? 1 : 0;

    k_prep<<<512, 64, 0, stream>>>(dict, ws);

    k_score<<<512, 512, 0, stream>>>(x, ws);   // static 50 KB LDS

    const int emit_lds = 33288 * 4;
    hipFuncSetAttribute((const void*)k_emit,
                        hipFuncAttributeMaxDynamicSharedMemorySize, emit_lds);
    k_emit<<<NBLK, 512, emit_lds, stream>>>(x, ws, out, use_part);

    if (use_part) k_reduce<<<260, 128, 0, stream>>>(ws);

    k_final<<<1, 512, 0, stream>>>(ws, csz, davg, out);
}

// Round 21
// 126.233 us; speedup vs baseline: 1.2067x; 1.2067x over previous
//
#include <hip/hip_runtime.h>
#include <math.h>

#define DIMC 64
#define NE 512
#define HWSZ 4096              // 64*64
#define NPTS 131072
#define DECAYF 0.99f
#define OMD 0.01f
#define EPSF 1e-5f
#define MARGIN 1e-3f

// output offsets (floats) — out0 is [32,64,64,64] = 8388608 elements
#define O0 0
#define O1 8388608                 // diff scalar
#define O2 8388609                 // embed_ind [32,64,64]
#define O3 8519681                 // new_cluster_size [512]
#define O4 8520193                 // new_dictionary_avg [64,512]
#define O5 8552961                 // new_dictionary [64,512]
#define O6 8585729                 // mean_D scalar

// ws float-offset layout (r14-proven)
#define WS_DIFF   0
#define WS_ESUM   64                       // [c][j] 64*512 f32 (reduced)
#define WS_COUNTS 32832                    // 512 f32 (contiguous after ESUM)
#define WS_DT     33344                    // [j][c] dictT f32, 32768
#define WS_NORM   66112                    // 512: -0.5*||d_j||^2
#define WS_DHI    66624                    // 512x64 bf16 (16384 floats)
#define WS_DLO    83008                    // 512x64 bf16
#define WS_PART   246852                   // f32 partials: NBLK x 33280
#define PART_STRIDE 33280                  // 32768 esum + 512 counts
#define NBLK 256
#define WS_NEED_BYTES ((size_t)(WS_PART + (size_t)NBLK * PART_STRIDE) * 4)

typedef __attribute__((ext_vector_type(8))) short bf16x8;
typedef __attribute__((ext_vector_type(4))) float f32x4;

__device__ __forceinline__ unsigned bf16rne(float x) {
    unsigned u = __float_as_uint(x);
    return (u + 0x7FFFu + ((u >> 16) & 1u)) >> 16;
}

// -------- K1: dictT f32 + bf16 hi/lo + norms + zero accumulators --------
__global__ void k_prep(const float* __restrict__ dict, float* __restrict__ ws) {
    int j = blockIdx.x, c = threadIdx.x;
    float v = dict[c * NE + j];
    ws[WS_DT + j * DIMC + c] = v;
    unsigned h = bf16rne(v);
    float fh = __uint_as_float(h << 16);
    unsigned l = bf16rne(v - fh);
    ((unsigned short*)(ws + WS_DHI))[j * DIMC + c] = (unsigned short)h;
    ((unsigned short*)(ws + WS_DLO))[j * DIMC + c] = (unsigned short)l;
    ws[WS_ESUM + j * DIMC + c] = 0.f;      // fallback path target
    if (c == 0) ws[WS_COUNTS + j] = 0.f;
    if (j == 0 && c == 0) ws[WS_DIFF] = 0.f;
    float s = v * v;
    #pragma unroll
    for (int off = 32; off > 0; off >>= 1) s += __shfl_down(s, off);
    if (c == 0) ws[WS_NORM + j] = -0.5f * s;
}

#define MFMA16(A, B, C) __builtin_amdgcn_mfma_f32_16x16x32_bf16(A, B, C, 0, 0, 0)

// -------- K2: fused MFMA score (dict in LDS) + rescan + emit + partials --
// 256 blocks x 512 threads (8 waves); wave computes 64 points x 512 codes.
// The 128 KB LDS region is time-multiplexed: x-staging -> dict hi/lo -> esum.
__global__ __launch_bounds__(512, 1) void k_main(
        const float* __restrict__ x, float* __restrict__ ws,
        float* __restrict__ out, int use_part) {
    extern __shared__ float lds[];
    char*  ldsB   = (char*)lds;          // region A (128 KB), multi-use
    float* esum   = lds;                 // phase3: esum_t [c][j] 64x512 f32
    int*   lhist  = (int*)(lds + 32768); // 512 (region B)
    int*   bidxl  = (int*)(lds + 33280); // 512
    int*   lflist = (int*)(lds + 33792); // 512
    int*   lcnt   = (int*)(lds + 34304); // 1
    float* lred   = lds + 34308;         // 8

    const int tid  = threadIdx.x;
    const int lane = tid & 63;
    const int w    = tid >> 6;

    const int nb = blockIdx.x * 512;
    const int n0 = nb + tid;
    const int b = n0 >> 12, hw0 = n0 & 4095;
    const float* xp = x + (size_t)b * (DIMC * HWSZ) + hw0;

    // ---- phase 1: load point + bf16 split + stage to LDS (chunk-XOR) ----
    float f0[DIMC];
    #pragma unroll
    for (int c = 0; c < DIMC; ++c) f0[c] = xp[c * HWSZ];
    {
        unsigned hiw[32], low[32];
        #pragma unroll
        for (int i = 0; i < 32; ++i) {
            unsigned h0 = bf16rne(f0[2 * i]);
            unsigned h1 = bf16rne(f0[2 * i + 1]);
            float fh0 = __uint_as_float(h0 << 16);
            float fh1 = __uint_as_float(h1 << 16);
            unsigned l0 = bf16rne(f0[2 * i] - fh0);
            unsigned l1 = bf16rne(f0[2 * i + 1] - fh1);
            hiw[i] = h0 | (h1 << 16);
            low[i] = l0 | (l1 << 16);
        }
        const int swz = tid & 7;
        #pragma unroll
        for (int k = 0; k < 8; ++k) {
            uint4 vh = {hiw[4 * k], hiw[4 * k + 1], hiw[4 * k + 2], hiw[4 * k + 3]};
            uint4 vl = {low[4 * k], low[4 * k + 1], low[4 * k + 2], low[4 * k + 3]};
            *(uint4*)(ldsB + tid * 128 + ((k ^ swz) << 4)) = vh;
            *(uint4*)(ldsB + 65536 + tid * 128 + ((k ^ swz) << 4)) = vl;
        }
    }
    lhist[tid] = 0;
    if (tid == 0) lcnt[0] = 0;
    __syncthreads();

    // ---- A-fragments (row = lane&15, k = (lane>>4)*8 + e, +32*kk) ----
    bf16x8 ahi[4][2], alo[4][2];
    #pragma unroll
    for (int pt = 0; pt < 4; ++pt) {
        const int arow = (w << 6) + (pt << 4) + (lane & 15);
        const int swz = arow & 7;
        #pragma unroll
        for (int kk = 0; kk < 2; ++kk) {
            const int ch = (lane >> 4) + (kk << 2);
            ahi[pt][kk] = __builtin_bit_cast(bf16x8,
                *(const uint4*)(ldsB + arow * 128 + ((ch ^ swz) << 4)));
            alo[pt][kk] = __builtin_bit_cast(bf16x8,
                *(const uint4*)(ldsB + 65536 + arow * 128 + ((ch ^ swz) << 4)));
        }
    }
    __syncthreads();   // x-staging dead -> region A reusable for dict

    // ---- phase 2: stage FULL dict bf16 hi/lo into region A (128 KB) ----
    {
        const uint4* gdh = (const uint4*)(ws + WS_DHI);   // 4096 uint4
        const uint4* gdl = (const uint4*)(ws + WS_DLO);
        uint4* LA = (uint4*)lds;
        #pragma unroll
        for (int k = 0; k < 8; ++k) {
            const int i = k * 512 + tid;           // [0, 4096)
            const int cl = i >> 3, ch = i & 7;     // code, chunk
            const int dp = cl * 8 + (ch ^ (cl & 7));
            LA[dp] = gdh[i];
            LA[4096 + dp] = gdl[i];
        }
    }
    __syncthreads();

    // ---- MFMA sweep over 32 code-tiles; B from LDS (conflict-free) ----
    const uint4* Lh = (const uint4*)lds;
    const uint4* Ll = Lh + 4096;
    const int col = lane & 15, g = lane >> 4;
    const int cswz = col & 7;
    const float* npl = ws + WS_NORM + col;

    float best[4][4], sec[4][4];
    int   idx[4][4];
    #pragma unroll
    for (int pt = 0; pt < 4; ++pt)
        #pragma unroll
        for (int r = 0; r < 4; ++r) {
            best[pt][r] = -3.4e38f; sec[pt][r] = -3.4e38f; idx[pt][r] = 0;
        }

    #pragma unroll 2
    for (int jt = 0; jt < 32; ++jt) {
        const int base = (jt << 7) + (col << 3);
        uint4 uh0 = Lh[base + (g ^ cswz)];
        uint4 uh1 = Lh[base + ((g + 4) ^ cswz)];
        uint4 ul0 = Ll[base + (g ^ cswz)];
        uint4 ul1 = Ll[base + ((g + 4) ^ cswz)];
        float nrm = npl[jt << 4];
        bf16x8 bh0 = __builtin_bit_cast(bf16x8, uh0);
        bf16x8 bh1 = __builtin_bit_cast(bf16x8, uh1);
        bf16x8 bl0 = __builtin_bit_cast(bf16x8, ul0);
        bf16x8 bl1 = __builtin_bit_cast(bf16x8, ul1);
        const int jc = (jt << 4) + col;
        #pragma unroll
        for (int pt = 0; pt < 4; ++pt) {
            f32x4 acc = {0.f, 0.f, 0.f, 0.f};
            acc = MFMA16(ahi[pt][0], bh0, acc);
            acc = MFMA16(ahi[pt][1], bh1, acc);
            acc = MFMA16(ahi[pt][0], bl0, acc);
            acc = MFMA16(ahi[pt][1], bl1, acc);
            acc = MFMA16(alo[pt][0], bh0, acc);
            acc = MFMA16(alo[pt][1], bh1, acc);
            acc = MFMA16(alo[pt][0], bl0, acc);
            acc = MFMA16(alo[pt][1], bl1, acc);
            #pragma unroll
            for (int r = 0; r < 4; ++r) {
                float s = acc[r] + nrm;
                bool gt = s > best[pt][r];
                float ns = gt ? best[pt][r] : (s > sec[pt][r] ? s : sec[pt][r]);
                best[pt][r] = gt ? s : best[pt][r];
                idx[pt][r]  = gt ? jc : idx[pt][r];
                sec[pt][r]  = ns;
            }
        }
    }

    // ---- argmax reduce across 16-lane code groups ----
    #pragma unroll
    for (int off = 8; off > 0; off >>= 1) {
        #pragma unroll
        for (int pt = 0; pt < 4; ++pt)
            #pragma unroll
            for (int r = 0; r < 4; ++r) {
                float ob = __shfl_xor(best[pt][r], off, 16);
                float os = __shfl_xor(sec[pt][r], off, 16);
                int   oi = __shfl_xor(idx[pt][r], off, 16);
                bool take = (ob > best[pt][r]) ||
                            (ob == best[pt][r] && oi < idx[pt][r]);
                float nsec = fmaxf(fminf(ob, best[pt][r]),
                                   fmaxf(os, sec[pt][r]));
                best[pt][r] = take ? ob : best[pt][r];
                idx[pt][r]  = take ? oi : idx[pt][r];
                sec[pt][r]  = nsec;
            }
    }
    if ((lane & 15) == 0) {
        const int gq = lane >> 4;
        #pragma unroll
        for (int pt = 0; pt < 4; ++pt)
            #pragma unroll
            for (int r = 0; r < 4; ++r) {
                int p = (w << 6) + (pt << 4) + (gq << 2) + r;
                int flag = (best[pt][r] - sec[pt][r] < MARGIN) ? 65536 : 0;
                bidxl[p] = idx[pt][r] | flag;
            }
    }
    __syncthreads();

    // ---- build flagged list ----
    {
        int e = bidxl[tid];
        if (e & 65536) {
            int pos = atomicAdd(lcnt, 1);
            lflist[pos] = tid;
        }
    }
    __syncthreads();

    // ---- in-block exact rescan, one wave per flagged point (inline shfl) --
    const float* dptr = ws + WS_DT;
    {
        const int nf = lcnt[0];
        const int hwb = nb & 4095;
        for (int fi = w; fi < nf; fi += 8) {
            const int pp = lflist[fi];
            const float xv = x[(size_t)b * (DIMC * HWSZ)
                               + (size_t)lane * HWSZ + hwb + pp];
            float bb = -3.4e38f; int bj = 0;
            #pragma unroll 2
            for (int s = 0; s < 8; ++s) {
                const int j = (lane << 3) + s;
                const float4* row = (const float4*)(dptr + (size_t)j * DIMC);
                float a0 = 0.f, a1 = 0.f, a2 = 0.f, a3 = 0.f;
                #pragma unroll
                for (int c4 = 0; c4 < 16; ++c4) {
                    float4 r4 = row[c4];
                    a0 = fmaf(r4.x, __shfl(xv, 4 * c4 + 0), a0);
                    a1 = fmaf(r4.y, __shfl(xv, 4 * c4 + 1), a1);
                    a2 = fmaf(r4.z, __shfl(xv, 4 * c4 + 2), a2);
                    a3 = fmaf(r4.w, __shfl(xv, 4 * c4 + 3), a3);
                }
                float sc = ((a0 + a1) + (a2 + a3)) + ws[WS_NORM + j];
                if (sc > bb) { bb = sc; bj = j; }
            }
            #pragma unroll
            for (int off = 1; off < 64; off <<= 1) {
                float ob = __shfl_xor(bb, off);
                int   oi = __shfl_xor(bj, off);
                bool take = (ob > bb) || (ob == bb && oi < bj);
                bb = take ? ob : bb;
                bj = take ? oi : bj;
            }
            if (lane == 0) bidxl[pp] = bj;
        }
    }
    __syncthreads();   // dict region dead -> phase 3: esum

    // ---- zero esum region (overwrites dict) ----
    {
        float4 z = {0.f, 0.f, 0.f, 0.f};
        float4* e4 = (float4*)lds;
        #pragma unroll
        for (int k = 0; k < 16; ++k) e4[tid + 512 * k] = z;
    }
    __syncthreads();

    // ---- emit with FINAL indices: hist, embed_ind, quantize, diff, esum --
    const int bi0 = bidxl[tid] & 511;
    atomicAdd(&lhist[bi0], 1);
    out[O2 + n0] = (float)bi0;

    float ssum = 0.f;
    float* o0 = out + O0 + (size_t)b * (DIMC * HWSZ) + hw0;
    const float4* q40 = (const float4*)(dptr + (size_t)bi0 * DIMC);
    #pragma unroll
    for (int c4 = 0; c4 < 16; ++c4) {
        float4 qa = q40[c4];
        const int cb = 4 * c4;
        o0[(cb + 0) * HWSZ] = qa.x;
        o0[(cb + 1) * HWSZ] = qa.y;
        o0[(cb + 2) * HWSZ] = qa.z;
        o0[(cb + 3) * HWSZ] = qa.w;
        float d;
        d = qa.x - f0[cb + 0]; ssum = fmaf(d, d, ssum);
        d = qa.y - f0[cb + 1]; ssum = fmaf(d, d, ssum);
        d = qa.z - f0[cb + 2]; ssum = fmaf(d, d, ssum);
        d = qa.w - f0[cb + 3]; ssum = fmaf(d, d, ssum);
    }

    #pragma unroll
    for (int c = 0; c < DIMC; ++c) atomicAdd(&esum[c * NE + bi0], f0[c]);
    __syncthreads();

    if (use_part) {
        float* part = ws + WS_PART + (size_t)blockIdx.x * PART_STRIDE;
        float4* p4 = (float4*)part;
        const float4* e4 = (const float4*)esum;
        #pragma unroll
        for (int k = 0; k < 16; ++k) p4[tid + 512 * k] = e4[tid + 512 * k];
        part[32768 + tid] = (float)lhist[tid];
    } else {
        #pragma unroll
        for (int k = 0; k < 64; ++k)
            atomicAdd(&ws[WS_ESUM + tid + 512 * k], esum[tid + 512 * k]);
        atomicAdd(&ws[WS_COUNTS + tid], (float)lhist[tid]);
    }

    // diff reduction (8 waves)
    #pragma unroll
    for (int off = 32; off > 0; off >>= 1) ssum += __shfl_down(ssum, off);
    if ((tid & 63) == 0) lred[tid >> 6] = ssum;
    __syncthreads();
    if (tid == 0) {
        float t = 0.f;
        #pragma unroll
        for (int w2 = 0; w2 < 8; ++w2) t += lred[w2];
        atomicAdd(ws + WS_DIFF, t);
    }
}

// -------- K2d: parallel partial reduce (260 blocks, spread atomics) ------
__global__ void k_reduce(float* __restrict__ ws) {
    const int tid = threadIdx.x;
    const int gid = (blockIdx.x % 65) * 128 + tid;     // [0, 8320) float4 pos
    const int slice = blockIdx.x / 65;                  // [0, 4)
    const float4* src = (const float4*)(ws + WS_PART);
    float4 acc = {0.f, 0.f, 0.f, 0.f};
    const int p0 = slice * 64;
    #pragma unroll 4
    for (int p = p0; p < p0 + 64; ++p) {
        float4 v = src[(size_t)p * (PART_STRIDE / 4) + gid];
        acc.x += v.x; acc.y += v.y; acc.z += v.z; acc.w += v.w;
    }
    float* dst = ws + WS_ESUM + gid * 4;                // COUNTS follows ESUM
    atomicAdd(dst + 0, acc.x);
    atomicAdd(dst + 1, acc.y);
    atomicAdd(dst + 2, acc.z);
    atomicAdd(dst + 3, acc.w);
}

// -------- K3: finalize EMA buffers / outputs --------
__global__ void k_final(const float* __restrict__ ws,
                        const float* __restrict__ cluster_size,
                        const float* __restrict__ davg,
                        float* __restrict__ out) {
    __shared__ float red[16];
    __shared__ float nsh;
    const int j = threadIdx.x;

    float cnt = ws[WS_COUNTS + j];
    float ncs = DECAYF * cluster_size[j] + OMD * cnt;
    out[O3 + j] = ncs;

    float v = ncs;
    #pragma unroll
    for (int off = 32; off > 0; off >>= 1) v += __shfl_down(v, off);
    if ((j & 63) == 0) red[j >> 6] = v;
    __syncthreads();
    if (j == 0) {
        float t = 0.f;
        #pragma unroll
        for (int w = 0; w < 8; ++w) t += red[w];
        nsh = t;
    }
    __syncthreads();
    const float n = nsh;
    const float csj = (ncs + EPSF) / (n + NE * EPSF) * n;

    float asum = 0.f;
    #pragma unroll
    for (int c = 0; c < DIMC; ++c) {
        float es = ws[WS_ESUM + c * NE + j];
        float da = davg[c * NE + j];
        float nda = DECAYF * da + OMD * es;
        out[O4 + c * NE + j] = nda;
        float nd = nda / csj;
        out[O5 + c * NE + j] = nd;
        asum += fabsf(nd);
    }

    __syncthreads();
    #pragma unroll
    for (int off = 32; off > 0; off >>= 1) asum += __shfl_down(asum, off);
    if ((j & 63) == 0) red[j >> 6] = asum;
    __syncthreads();
    if (j == 0) {
        float t = 0.f;
        #pragma unroll
        for (int w = 0; w < 8; ++w) t += red[w];
        out[O6] = t / 32768.0f;
        out[O1] = ws[WS_DIFF] / 8388608.0f;
    }
}

extern "C" void kernel_launch(void* const* d_in, const int* in_sizes, int n_in,
                              void* d_out, int out_size, void* d_ws, size_t ws_size,
                              hipStream_t stream) {
    const float* x    = (const float*)d_in[0];
    const float* dict = (const float*)d_in[1];
    const float* csz  = (const float*)d_in[2];
    const float* davg = (const float*)d_in[3];
    float* out = (float*)d_out;
    float* ws  = (float*)d_ws;

    const int use_part = (ws_size >= WS_NEED_BYTES) ? 1 : 0;

    k_prep<<<512, 64, 0, stream>>>(dict, ws);

    const int main_lds = 34320 * 4;   // 137.3 KB (1 block/CU)
    hipFuncSetAttribute((const void*)k_main,
                        hipFuncAttributeMaxDynamicSharedMemorySize, main_lds);
    k_main<<<NBLK, 512, main_lds, stream>>>(x, ws, out, use_part);

    if (use_part) k_reduce<<<260, 128, 0, stream>>>(ws);

    k_final<<<1, 512, 0, stream>>>(ws, csz, davg, out);
}